// Round 7
// baseline (234.695 us; speedup 1.0000x reference)
//
#include <hip/hip_runtime.h>
#include <math.h>

#define XROWS 12544      // 256*49
#define YROWS 2048       // 64*32
#define HD 512
#define NM 49
#define NL 32
#define MP1 50
#define LP1 33
#define BSTRIDE 1650     // (m+1)*(L+1)
#define INVREG 10.0f

typedef __attribute__((ext_vector_type(8))) short short8;
typedef __attribute__((ext_vector_type(4))) float floatx4;

__device__ __forceinline__ unsigned short f2bf(float f) {
    unsigned int u = __builtin_bit_cast(unsigned int, f);
    u = (u + 0x7FFFu + ((u >> 16) & 1u)) >> 16;
    return (unsigned short)u;
}

__device__ __forceinline__ void gload_lds16(const void* g, void* l) {
    typedef const __attribute__((address_space(1))) unsigned int* gp_t;
    typedef __attribute__((address_space(3))) unsigned int* lp_t;
    __builtin_amdgcn_global_load_lds((gp_t)g, (lp_t)l, 16, 0, 0);
}

__device__ __forceinline__ float rl(float v, int l) {   // wave-uniform broadcast (SGPR)
    return __builtin_bit_cast(float, __builtin_amdgcn_readlane(__builtin_bit_cast(int, v), l));
}

// ------------------------------------------------ normalize + cast to bf16
__global__ __launch_bounds__(256) void normcvt_kernel(
    const float* __restrict__ x, const float* __restrict__ y,
    unsigned short* __restrict__ xb, unsigned short* __restrict__ yb)
{
    const int wid = blockIdx.x * 4 + (threadIdx.x >> 6);
    const int lane = threadIdx.x & 63;
    if (wid >= XROWS + YROWS) return;
    const float* src;
    unsigned short* dst;
    if (wid < XROWS) { src = x + (size_t)wid * HD;           dst = xb + (size_t)wid * HD; }
    else             { src = y + (size_t)(wid - XROWS) * HD; dst = yb + (size_t)(wid - XROWS) * HD; }
    const float4 v0 = *(const float4*)(src + lane * 8);
    const float4 v1 = *(const float4*)(src + lane * 8 + 4);
    float s = v0.x*v0.x + v0.y*v0.y + v0.z*v0.z + v0.w*v0.w
            + v1.x*v1.x + v1.y*v1.y + v1.z*v1.z + v1.w*v1.w;
    #pragma unroll
    for (int o = 32; o > 0; o >>= 1) s += __shfl_xor(s, o, 64);
    const float inv = 1.0f / fmaxf(sqrtf(s), 1e-12f);
    short8 ov;
    ov[0] = (short)f2bf(v0.x * inv); ov[1] = (short)f2bf(v0.y * inv);
    ov[2] = (short)f2bf(v0.z * inv); ov[3] = (short)f2bf(v0.w * inv);
    ov[4] = (short)f2bf(v1.x * inv); ov[5] = (short)f2bf(v1.y * inv);
    ov[6] = (short)f2bf(v1.z * inv); ov[7] = (short)f2bf(v1.w * inv);
    *(short8*)(dst + lane * 8) = ov;
}

// ------------------------------------------------ bf16 MFMA GEMM
// C[12544 x 2048] = Xb * Yb^T, scattered into d_out at ((i*64+j)*1650 + p*32+l)
#define BM 128
#define BN 128
#define BK 32

__global__ __launch_bounds__(256) void mfma_gemm_kernel(
    const unsigned short* __restrict__ xb, const unsigned short* __restrict__ yb,
    float* __restrict__ outS)
{
    __shared__ unsigned short lA[BM * BK];   // 8 KB, row-major [128][32]
    __shared__ unsigned short lB[BN * BK];   // 8 KB, row-major [128][32]
    const int tid  = threadIdx.x;
    const int lane = tid & 63;
    const int wv   = tid >> 6;          // wave 0..3
    const int wr   = wv >> 1, wc = wv & 1;
    const int mblk = blockIdx.x >> 4;   // 0..97
    const int nblk = blockIdx.x & 15;   // fastest -> A-tile L2 reuse
    const int m0 = mblk * BM, n0 = nblk * BN;

    floatx4 acc[4][4] = {};

    const int srow = tid >> 2;          // 0..63 (staging row within pass)
    const int skq  = (tid & 3) * 8;     // k offset, 8 bf16 = 16 B

    for (int kt = 0; kt < HD / BK; ++kt) {
        const int k0 = kt * BK;
        __syncthreads();                 // previous compute done before overwrite
        gload_lds16(xb + (size_t)(m0 +      srow) * HD + k0 + skq, (char*)lA +        wv * 1024);
        gload_lds16(xb + (size_t)(m0 + 64 + srow) * HD + k0 + skq, (char*)lA + 4096 + wv * 1024);
        gload_lds16(yb + (size_t)(n0 +      srow) * HD + k0 + skq, (char*)lB +        wv * 1024);
        gload_lds16(yb + (size_t)(n0 + 64 + srow) * HD + k0 + skq, (char*)lB + 4096 + wv * 1024);
        __syncthreads();                 // compiler drains vmcnt(0) here

        const int krow = (lane >> 4) * 8;
        short8 aF[4], bF[4];
        #pragma unroll
        for (int mi = 0; mi < 4; ++mi)
            aF[mi] = *(const short8*)&lA[(wr * 64 + mi * 16 + (lane & 15)) * BK + krow];
        #pragma unroll
        for (int ni = 0; ni < 4; ++ni)
            bF[ni] = *(const short8*)&lB[(wc * 64 + ni * 16 + (lane & 15)) * BK + krow];
        #pragma unroll
        for (int mi = 0; mi < 4; ++mi)
            #pragma unroll
            for (int ni = 0; ni < 4; ++ni)
                acc[mi][ni] = __builtin_amdgcn_mfma_f32_16x16x32_bf16(
                    aF[mi], bF[ni], acc[mi][ni], 0, 0, 0);
    }

    // epilogue: C/D layout col=lane&15, row=(lane>>4)*4+q  (m89-verified)
    #pragma unroll
    for (int mi = 0; mi < 4; ++mi) {
        #pragma unroll
        for (int q = 0; q < 4; ++q) {
            const int r = m0 + wr * 64 + mi * 16 + (lane >> 4) * 4 + q;
            const int i = r / NM;
            const int p = r - i * NM;
            #pragma unroll
            for (int ni = 0; ni < 4; ++ni) {
                const int c = n0 + wc * 64 + ni * 16 + (lane & 15);
                const int j = c >> 5, lc = c & 31;
                outS[(size_t)(i * 64 + j) * BSTRIDE + p * 32 + lc] = acc[mi][ni][q];
            }
        }
    }
}

// ---------------------------------------------------------------- sinkhorn: one wave per pair
// Multiplicative form, fully register-resident: lane p holds K row p (33 VGPR),
// lane l holds K col l (50 VGPR, via one-time LDS transpose). Broadcasts via
// v_readlane -> SGPR. Inner loop: zero LDS ops, zero barriers.
// __launch_bounds__(64,4): <=128 unified regs -> arrays stay in arch VGPRs
// (round-6 at 256 thr had VGPR_Count=56 => AGPR shuttling, 2.5x VALU bloat).
__global__ __launch_bounds__(64, 4) void sinkhorn_kernel(
    float* __restrict__ outZ,
    const int* __restrict__ ymask,
    const float* __restrict__ d_im, const float* __restrict__ d_lang,
    float* __restrict__ scores2)
{
    const int lane = threadIdx.x;          // 0..63
    const int b = blockIdx.x;
    const int j = b & 63;
    __shared__ float zs[1684];             // transpose scratch, then Zm staging
    float* base = outZ + (size_t)b * BSTRIDE;

    const int mval = (lane < NL) ? (ymask[j * NL + lane] != 0) : 1;
    const unsigned long long vb = __ballot(lane < NL && !mval);  // bit c = col c valid
    const float ns = (float)__popcll(vb);
    const float kim   = __expf(fminf(fmaxf(d_im[0],   -1.f), 1.f) * INVREG);
    const float klang = __expf(fminf(fmaxf(d_lang[0], -1.f), 1.f) * INVREG);

    // ---- build K row in registers ----
    float kr[33];
    #pragma unroll
    for (int c = 0; c < 33; ++c) kr[c] = 0.f;
    if (lane < NM) {
        #pragma unroll
        for (int h = 0; h < 16; ++h) {     // float2: base is only 8B-aligned
            const float2 v = *(const float2*)(base + lane * NL + h * 2);
            kr[h*2]   = ((vb >> (h*2))   & 1ull) ? __expf(v.x * INVREG) : 0.f;
            kr[h*2+1] = ((vb >> (h*2+1)) & 1ull) ? __expf(v.y * INVREG) : 0.f;
        }
    } else if (lane == NM) {               // dustbin row p=49
        #pragma unroll
        for (int c = 0; c < NL; ++c) kr[c] = ((vb >> c) & 1ull) ? klang : 0.f;
    }
    kr[32] = kim;

    // ---- one-time transpose to get K col in registers (lanes 0..32) ----
    if (lane < MP1) {
        #pragma unroll
        for (int c = 0; c < 33; ++c) zs[c * 51 + lane] = kr[c];
    }
    asm volatile("s_waitcnt lgkmcnt(0)" ::: "memory");
    __builtin_amdgcn_sched_barrier(0);
    float kc[50];
    #pragma unroll
    for (int p = 0; p < 50; ++p) kc[p] = 0.f;
    if (lane < LP1) {
        #pragma unroll
        for (int p = 0; p < 50; ++p) kc[p] = zs[lane * 51 + p];
    }

    const float mup = (lane < NM) ? 1.f : ns;     // lane 49 -> ns
    const float nup = (lane < NL) ? 1.f : 49.f;   // lane 32 -> m
    const bool colA = (lane < NL) ? (((vb >> lane) & 1ull) != 0ull) : (lane == NL);
    float eu = 0.f;
    float ev = colA ? 1.f : 0.f;

    // ---- 10 iterations, pure VALU/SALU ----
    for (int it = 0; it < 10; ++it) {
        float a0 = 0.f, a1 = 0.f, a2 = 0.f, a3 = 0.f;
        #pragma unroll
        for (int c = 0; c < 33; c += 4) {
            a0 = fmaf(kr[c], rl(ev, c), a0);
            if (c + 1 < 33) a1 = fmaf(kr[c+1], rl(ev, c+1), a1);
            if (c + 2 < 33) a2 = fmaf(kr[c+2], rl(ev, c+2), a2);
            if (c + 3 < 33) a3 = fmaf(kr[c+3], rl(ev, c+3), a3);
        }
        eu = __fdividef(mup, (a0 + a1) + (a2 + a3));

        a0 = a1 = a2 = a3 = 0.f;
        #pragma unroll
        for (int p = 0; p < 50; p += 4) {
            a0 = fmaf(kc[p], rl(eu, p), a0);
            if (p + 1 < 50) a1 = fmaf(kc[p+1], rl(eu, p+1), a1);
            if (p + 2 < 50) a2 = fmaf(kc[p+2], rl(eu, p+2), a2);
            if (p + 3 < 50) a3 = fmaf(kc[p+3], rl(eu, p+3), a3);
        }
        const float Sv = (a0 + a1) + (a2 + a3);
        ev = colA ? __fdividef(nup, Sv) : 0.f;
    }

    // ---- epilogue: Zm = K*eu*ev staged to LDS; ot from lnK (= score/TEMP) ----
    float ot = 0.f;
    if (lane < MP1) {
        #pragma unroll
        for (int c = 0; c < 33; ++c) {
            const float zm = kr[c] * eu * rl(ev, c);
            zs[lane * 33 + c] = zm;
            if (lane < NM && c < NL && kr[c] > 0.f)
                ot = fmaf(__logf(kr[c]), zm, ot);   // lnK = 10*score = score/TEMP
        }
    }
    #pragma unroll
    for (int o = 32; o > 0; o >>= 1) ot += __shfl_xor(ot, o, 64);
    if (lane == 0) scores2[b] = ot;
    asm volatile("s_waitcnt lgkmcnt(0)" ::: "memory");
    __builtin_amdgcn_sched_barrier(0);
    // coalesced writeback: 1650 floats = 825 float2
    #pragma unroll
    for (int t = 0; t < 13; ++t) {
        const int idx = t * 64 + lane;
        if (idx < 825) *(float2*)(base + idx * 2) = *(const float2*)&zs[idx * 2];
    }
}

// ---------------------------------------------------------------- InfoNCE loss
__global__ __launch_bounds__(256) void loss_kernel(
    const float* __restrict__ s2, float* __restrict__ out)
{
    const int i = threadIdx.x;
    const int g = i >> 2;
    const float pos = s2[i * 64 + g];
    float mx = -3.0e38f;
    for (int jj = 0; jj < 64; ++jj) mx = fmaxf(mx, s2[i * 64 + jj]);
    float sm = 0.f;
    for (int jj = 0; jj < 64; ++jj) sm += __expf(s2[i * 64 + jj] - mx);
    const float lse1 = __logf(sm) + mx;

    float mx2 = -3.0e38f;
    for (int k = 0; k < 256; ++k) {
        const bool allowed = ((k >> 2) != g) || (k == i);
        if (allowed) mx2 = fmaxf(mx2, s2[k * 64 + g]);
    }
    float sm2 = 0.f;
    for (int k = 0; k < 256; ++k) {
        const bool allowed = ((k >> 2) != g) || (k == i);
        if (allowed) sm2 += __expf(s2[k * 64 + g] - mx2);
    }
    const float lse2 = __logf(sm2) + mx2;

    float li = 0.5f * (lse1 - pos) + 0.5f * (lse2 - pos);
    #pragma unroll
    for (int o = 32; o > 0; o >>= 1) li += __shfl_xor(li, o, 64);
    __shared__ float wred[4];
    if ((i & 63) == 0) wred[i >> 6] = li;
    __syncthreads();
    if (i == 0) out[0] = (wred[0] + wred[1] + wred[2] + wred[3]) * (1.0f / 256.0f);
}

// ---------------------------------------------------------------- launch
extern "C" void kernel_launch(void* const* d_in, const int* in_sizes, int n_in,
                              void* d_out, int out_size, void* d_ws, size_t ws_size,
                              hipStream_t stream)
{
    const float* x      = (const float*)d_in[0];
    const float* y      = (const float*)d_in[1];
    const float* d_im   = (const float*)d_in[2];
    const float* d_lang = (const float*)d_in[3];
    const int* ymask    = (const int*)d_in[4];
    float* out = (float*)d_out;
    float* ws  = (float*)d_ws;

    float* s2          = ws;                                  // 16384 floats
    unsigned short* xb = (unsigned short*)(ws + 16384);       // 12544*512 bf16
    unsigned short* yb = xb + (size_t)XROWS * HD;             // 2048*512 bf16

    normcvt_kernel<<<(XROWS + YROWS + 3) / 4, 256, 0, stream>>>(x, y, xb, yb);
    mfma_gemm_kernel<<<(XROWS / BM) * (YROWS / BN), 256, 0, stream>>>(xb, yb, out);
    sinkhorn_kernel<<<16384, 64, 0, stream>>>(out, ymask, d_im, d_lang, s2);
    loss_kernel<<<1, 256, 0, stream>>>(s2, out + (size_t)16384 * BSTRIDE);
}